// Round 2
// baseline (403.596 us; speedup 1.0000x reference)
//
#include <hip/hip_runtime.h>
#include <cstdint>
#include <cstddef>

#define BATCH 8192
#define IN_F 1024
#define OUT_F 1024
#define NSPL 9               // 1 base channel + 8 spline basis channels
#define KDIM (IN_F * NSPL)   // 9216

typedef __bf16 bf16x8 __attribute__((ext_vector_type(8)));
typedef float f32x4 __attribute__((ext_vector_type(4)));

// ---------------------------------------------------------------------------
// async global->LDS, 16B per lane. LDS dest is wave-uniform base + lane*16.
// ---------------------------------------------------------------------------
__device__ __forceinline__ void g2l16(const void* g, void* l) {
  __builtin_amdgcn_global_load_lds(
      (__attribute__((address_space(1))) void*)(g),
      (__attribute__((address_space(3))) void*)(l),
      16, 0, 0);
}

// ---------------------------------------------------------------------------
// Kernel 1: combined weight, B^T layout: Wt[o][i*9+r], bf16.
//   r=0: base_weight[o][i];  r=1..8: spline_weight[i][r-1][o]*spline_scaler[i][o]
// ---------------------------------------------------------------------------
__global__ void build_w(const float* __restrict__ bw, const float* __restrict__ sw,
                        const float* __restrict__ sc, __bf16* __restrict__ Wt) {
  const int o = blockIdx.x;
  const int tid = threadIdx.x;
#pragma unroll
  for (int c = 0; c < IN_F / 256; ++c) {
    const int i = c * 256 + tid;
    const float base = bw[(size_t)o * IN_F + i];
    const float scal = sc[(size_t)i * OUT_F + o];
    __bf16* dst = Wt + (size_t)o * KDIM + (size_t)i * NSPL;
    dst[0] = (__bf16)base;
#pragma unroll
    for (int r = 0; r < 8; ++r)
      dst[1 + r] = (__bf16)(sw[((size_t)i * 8 + r) * OUT_F + o] * scal);
  }
}

// ---------------------------------------------------------------------------
// Kernel 2: augmented activations A[b][i*9+r], bf16.
//   r=0: silu(x);  r=1..8: uniform cubic B-spline basis (closed form).
// Staged through LDS so the 151MB global write is coalesced uint4.
// ---------------------------------------------------------------------------
__global__ void build_a(const float* __restrict__ x, __bf16* __restrict__ A) {
  __shared__ __align__(16) __bf16 rowbuf[KDIM];  // 18432 B
  const int b = blockIdx.x;
  const int tid = threadIdx.x;
#pragma unroll
  for (int c = 0; c < IN_F / 256; ++c) {
    const int i = c * 256 + tid;
    const float v = x[(size_t)b * IN_F + i];
    float w[NSPL];
#pragma unroll
    for (int r = 0; r < NSPL; ++r) w[r] = 0.f;
    // silu
    w[0] = v / (1.f + __expf(-v));
    // uniform cubic B-spline: knots t_j = -2.2 + 0.4*j, j=0..11; cells 0..10
    const float p = (v + 2.2f) * 2.5f;
    const int cell = (int)floorf(p);
    if (cell >= 0 && cell <= 10 && v < 2.2f) {
      const float t = p - (float)cell;
      const float t2 = t * t, t3 = t2 * t;
      const float omt = 1.f - t;
      const float b0 = (1.f / 6.f) * omt * omt * omt;                        // j = cell-3
      const float b1 = (1.f / 6.f) * (3.f * t3 - 6.f * t2 + 4.f);            // j = cell-2
      const float b2 = (1.f / 6.f) * (-3.f * t3 + 3.f * t2 + 3.f * t + 1.f); // j = cell-1
      const float b3 = (1.f / 6.f) * t3;                                     // j = cell
      const int j0 = cell - 3;
      if (j0 + 0 >= 0 && j0 + 0 <= 7) w[1 + j0 + 0] = b0;
      if (j0 + 1 >= 0 && j0 + 1 <= 7) w[1 + j0 + 1] = b1;
      if (j0 + 2 >= 0 && j0 + 2 <= 7) w[1 + j0 + 2] = b2;
      if (j0 + 3 >= 0 && j0 + 3 <= 7) w[1 + j0 + 3] = b3;
    }
    __bf16* d = rowbuf + (size_t)i * NSPL;
#pragma unroll
    for (int r = 0; r < NSPL; ++r) d[r] = (__bf16)w[r];
  }
  __syncthreads();
  // coalesced copy out: 9216 bf16 = 1152 uint4 (grid-stride: 1152 = 4.5*256,
  // the round-1 bug was integer-dividing this to 4 full iterations)
  const uint4* src = (const uint4*)rowbuf;
  uint4* dst = (uint4*)(A + (size_t)b * KDIM);
  for (int t = tid; t < KDIM * 2 / 16; t += 256)
    dst[t] = src[t];
}

// ---------------------------------------------------------------------------
// Kernel 3: GEMM  out[M=8192][N=1024] = A[M][K=9216] * Wt[N][K]^T   (gemm_bt)
// m97 structure: 128x128 tile, BK=32, 4 waves (2x2), each wave 64x64 via
// 4x4 mfma_f32_16x16x32_bf16. global_load_lds width=16 staging, 2-barrier.
// XCD swizzle: mb = bid&63, nb = bid>>6 -> each XCD sees an 8x8 (mb,nb)
// cross product for L2 tile reuse.
// ---------------------------------------------------------------------------
__global__ __launch_bounds__(256) void gemm_bt(const __bf16* __restrict__ A,
                                               const __bf16* __restrict__ W,
                                               float* __restrict__ out) {
  __shared__ __align__(16) __bf16 As[128 * 32];
  __shared__ __align__(16) __bf16 Bs[128 * 32];

  const int tid = threadIdx.x;
  const int wv = tid >> 6;
  const int lane = tid & 63;
  const int mb = blockIdx.x & 63;
  const int nb = blockIdx.x >> 6;
  const int m0 = mb * 128;
  const int n0 = nb * 128;
  const int wr = wv & 1;   // wave row (m)
  const int wc = wv >> 1;  // wave col (n)

  // --- staging coords: wave wv covers LDS rows [wv*32, wv*32+32)
  const int srow = wv * 32 + (lane >> 2);   // q=0 row
  const int scol = (lane & 3) * 8;
  const __bf16* gA0 = A + (size_t)(m0 + srow) * KDIM + scol;
  const __bf16* gA1 = gA0 + (size_t)16 * KDIM;
  const __bf16* gB0 = W + (size_t)(n0 + srow) * KDIM + scol;
  const __bf16* gB1 = gB0 + (size_t)16 * KDIM;
  __bf16* lA0 = As + wv * 1024;
  __bf16* lA1 = lA0 + 512;
  __bf16* lB0 = Bs + wv * 1024;
  __bf16* lB1 = lB0 + 512;

  // --- fragment LDS offsets: A[m=lane&15][k=quad*8+j] per operand row
  const int mrow = lane & 15;
  const int quad = lane >> 4;
  int aoff[4], boff[4];
#pragma unroll
  for (int mt = 0; mt < 4; ++mt) aoff[mt] = (wr * 64 + mt * 16 + mrow) * 32 + quad * 8;
#pragma unroll
  for (int nt = 0; nt < 4; ++nt) boff[nt] = (wc * 64 + nt * 16 + mrow) * 32 + quad * 8;

  f32x4 acc[4][4];
  const f32x4 zero = {0.f, 0.f, 0.f, 0.f};
#pragma unroll
  for (int mt = 0; mt < 4; ++mt)
#pragma unroll
    for (int nt = 0; nt < 4; ++nt) acc[mt][nt] = zero;

  for (int k0 = 0; k0 < KDIM; k0 += 32) {
    __syncthreads();  // previous iteration's LDS reads done
    g2l16(gA0 + k0, lA0);
    g2l16(gA1 + k0, lA1);
    g2l16(gB0 + k0, lB0);
    g2l16(gB1 + k0, lB1);
    __syncthreads();  // staging landed (compiler drains vmcnt before barrier)

    bf16x8 af[4], bf[4];
#pragma unroll
    for (int mt = 0; mt < 4; ++mt) af[mt] = *(const bf16x8*)(As + aoff[mt]);
#pragma unroll
    for (int nt = 0; nt < 4; ++nt) bf[nt] = *(const bf16x8*)(Bs + boff[nt]);
#pragma unroll
    for (int mt = 0; mt < 4; ++mt)
#pragma unroll
      for (int nt = 0; nt < 4; ++nt)
        acc[mt][nt] = __builtin_amdgcn_mfma_f32_16x16x32_bf16(af[mt], bf[nt],
                                                              acc[mt][nt], 0, 0, 0);
  }

  // epilogue: C/D layout col = lane&15, row = quad*4 + reg
#pragma unroll
  for (int mt = 0; mt < 4; ++mt) {
#pragma unroll
    for (int nt = 0; nt < 4; ++nt) {
      const int col = n0 + wc * 64 + nt * 16 + mrow;
      const int rbase = m0 + wr * 64 + mt * 16 + quad * 4;
#pragma unroll
      for (int r = 0; r < 4; ++r)
        out[(size_t)(rbase + r) * OUT_F + col] = acc[mt][nt][r];
    }
  }
}

// ---------------------------------------------------------------------------
extern "C" void kernel_launch(void* const* d_in, const int* in_sizes, int n_in,
                              void* d_out, int out_size, void* d_ws, size_t ws_size,
                              hipStream_t stream) {
  const float* x  = (const float*)d_in[0];
  // d_in[1] = grid: uniform linspace, folded into closed-form basis (unused)
  const float* bw = (const float*)d_in[2];  // [OUT_F, IN_F]
  const float* sw = (const float*)d_in[3];  // [IN_F, 8, OUT_F]
  const float* sc = (const float*)d_in[4];  // [IN_F, OUT_F]
  float* out = (float*)d_out;

  __bf16* Wt = (__bf16*)d_ws;                                   // [OUT_F][KDIM] 18.9 MB
  __bf16* Ab = (__bf16*)((char*)d_ws +
                         (size_t)OUT_F * KDIM * sizeof(__bf16)); // [BATCH][KDIM] 151 MB

  build_w<<<OUT_F, 256, 0, stream>>>(bw, sw, sc, Wt);
  build_a<<<BATCH, 256, 0, stream>>>(x, Ab);
  gemm_bt<<<(BATCH / 128) * (OUT_F / 128), 256, 0, stream>>>(Ab, Wt, out);
}

// Round 3
// 313.773 us; speedup vs baseline: 1.2863x; 1.2863x over previous
//
#include <hip/hip_runtime.h>
#include <cstdint>
#include <cstddef>

#define BATCH 8192
#define IN_F 1024
#define OUT_F 1024
#define NSPL 9               // 1 base channel + 8 spline basis channels
#define KDIM (IN_F * NSPL)   // 9216

typedef __bf16 bf16x8 __attribute__((ext_vector_type(8)));
typedef float f32x4 __attribute__((ext_vector_type(4)));

// async global->LDS, 16B/lane; LDS dest is wave-uniform base + lane*16
__device__ __forceinline__ void g2l16(const void* g, void* l) {
  __builtin_amdgcn_global_load_lds(
      (__attribute__((address_space(1))) void*)(g),
      (__attribute__((address_space(3))) void*)(l),
      16, 0, 0);
}

// ---------------------------------------------------------------------------
// Kernel 1: combined weight Wt[o][i*9+r] bf16, coalesced via 64o x 16i LDS tile.
//   r=0: base_weight[o][i]; r=1..8: spline_weight[i][r-1][o]*spline_scaler[i][o]
// Round-2 version did 9 scattered 4B reads/thread (~600MB line traffic, ~130us);
// this version reads sw/sc as 256B coalesced bursts.
// Grid: 16 o-tiles x 64 i-tiles = 1024 blocks, 256 threads.
// ---------------------------------------------------------------------------
__global__ void build_w(const float* __restrict__ bw, const float* __restrict__ sw,
                        const float* __restrict__ sc, __bf16* __restrict__ Wt) {
  __shared__ float s_sw[16 * 8 * 64];  // [i][r][oo] 32KB
  __shared__ float s_sc[16 * 64];      // [i][oo]     4KB
  __shared__ float s_bw[64 * 16];      // [oo][i]     4KB
  const int tid = threadIdx.x;
  const int o0 = (blockIdx.x & 15) * 64;
  const int i0 = (blockIdx.x >> 4) * 16;

#pragma unroll
  for (int it = 0; it < 32; ++it) {   // sw: 8192 floats
    const int t = it * 256 + tid;
    const int i = t >> 9, r = (t >> 6) & 7, oo = t & 63;
    s_sw[t] = sw[((size_t)(i0 + i) * 8 + r) * OUT_F + o0 + oo];
  }
#pragma unroll
  for (int it = 0; it < 4; ++it) {    // sc: 1024 floats
    const int t = it * 256 + tid;
    const int i = t >> 6, oo = t & 63;
    s_sc[t] = sc[(size_t)(i0 + i) * OUT_F + o0 + oo];
  }
#pragma unroll
  for (int it = 0; it < 4; ++it) {    // bw: 1024 floats
    const int t = it * 256 + tid;
    const int oo = t >> 4, ii = t & 15;
    s_bw[t] = bw[(size_t)(o0 + oo) * IN_F + i0 + ii];
  }
  __syncthreads();

  // write: thread covers (oo = tid/4, 4 i's) -> 36 contiguous bf16
  const int oo = tid >> 2;
  const int isub = (tid & 3) * 4;
#pragma unroll
  for (int is = 0; is < 4; ++is) {
    const int i = isub + is;
    __bf16* dst = Wt + (size_t)(o0 + oo) * KDIM + (size_t)(i0 + i) * NSPL;
    dst[0] = (__bf16)s_bw[oo * 16 + i];
    const float scal = s_sc[i * 64 + oo];
#pragma unroll
    for (int r = 0; r < 8; ++r)
      dst[1 + r] = (__bf16)(s_sw[i * 512 + r * 64 + oo] * scal);
  }
}

// ---------------------------------------------------------------------------
// Kernel 2: augmented activations A[b][i*9+r], bf16 (silu + closed-form
// uniform cubic B-spline), staged through LDS for coalesced uint4 writes.
// ---------------------------------------------------------------------------
__global__ void build_a(const float* __restrict__ x, __bf16* __restrict__ A) {
  __shared__ __align__(16) __bf16 rowbuf[KDIM];  // 18432 B
  const int b = blockIdx.x;
  const int tid = threadIdx.x;
#pragma unroll
  for (int c = 0; c < IN_F / 256; ++c) {
    const int i = c * 256 + tid;
    const float v = x[(size_t)b * IN_F + i];
    float w[NSPL];
#pragma unroll
    for (int r = 0; r < NSPL; ++r) w[r] = 0.f;
    w[0] = v / (1.f + __expf(-v));  // silu
    // uniform cubic B-spline: knots t_j = -2.2 + 0.4*j, j=0..11; cells 0..10
    const float p = (v + 2.2f) * 2.5f;
    const int cell = (int)floorf(p);
    if (cell >= 0 && cell <= 10 && v < 2.2f) {
      const float t = p - (float)cell;
      const float t2 = t * t, t3 = t2 * t;
      const float omt = 1.f - t;
      const float b0 = (1.f / 6.f) * omt * omt * omt;
      const float b1 = (1.f / 6.f) * (3.f * t3 - 6.f * t2 + 4.f);
      const float b2 = (1.f / 6.f) * (-3.f * t3 + 3.f * t2 + 3.f * t + 1.f);
      const float b3 = (1.f / 6.f) * t3;
      const int j0 = cell - 3;
      if (j0 + 0 >= 0 && j0 + 0 <= 7) w[1 + j0 + 0] = b0;
      if (j0 + 1 >= 0 && j0 + 1 <= 7) w[1 + j0 + 1] = b1;
      if (j0 + 2 >= 0 && j0 + 2 <= 7) w[1 + j0 + 2] = b2;
      if (j0 + 3 >= 0 && j0 + 3 <= 7) w[1 + j0 + 3] = b3;
    }
    __bf16* d = rowbuf + (size_t)i * NSPL;
#pragma unroll
    for (int r = 0; r < NSPL; ++r) d[r] = (__bf16)w[r];
  }
  __syncthreads();
  const uint4* src = (const uint4*)rowbuf;
  uint4* dst = (uint4*)(A + (size_t)b * KDIM);
  for (int t = tid; t < KDIM * 2 / 16; t += 256)  // 1152 uint4, grid-stride
    dst[t] = src[t];
}

// ---------------------------------------------------------------------------
// Kernel 3: GEMM out[8192][1024] = A[8192][9216] * Wt[1024][9216]^T
// m97 structure, BK=64 as TWO 32-wide sub-tiles (As[2][128][32]) so the LDS
// bank pattern & 64B-segment global coalescing stay identical to the proven
// BK=32 layout while halving barrier-drain count (288 -> 144 k-steps).
// 128x128 tile, 4 waves (2x2), 4x4 mfma_f32_16x16x32_bf16 per wave per chunk.
// ---------------------------------------------------------------------------
__global__ __launch_bounds__(256) void gemm_bt(const __bf16* __restrict__ A,
                                               const __bf16* __restrict__ W,
                                               float* __restrict__ out) {
  __shared__ __align__(16) __bf16 As[2 * 128 * 32];  // 16KB
  __shared__ __align__(16) __bf16 Bs[2 * 128 * 32];  // 16KB

  const int tid = threadIdx.x;
  const int wv = tid >> 6;
  const int lane = tid & 63;
  const int mb = blockIdx.x & 63;
  const int nb = blockIdx.x >> 6;
  const int m0 = mb * 128;
  const int n0 = nb * 128;
  const int wr = wv & 1;   // wave row (m)
  const int wc = wv >> 1;  // wave col (n)

  // staging: wave wv covers rows [wv*32, wv*32+32); instr stages 16 rows x 32 cols
  const int srow = lane >> 2;          // 0..15
  const int scol = (lane & 3) * 8;     // 0,8,16,24
  const __bf16* gA = A + (size_t)(m0 + wv * 32 + srow) * KDIM + scol;
  const __bf16* gB = W + (size_t)(n0 + wv * 32 + srow) * KDIM + scol;
  __bf16* lA = As + wv * 1024;
  __bf16* lB = Bs + wv * 1024;

  // fragment LDS offsets (within one 128x32 sub-tile)
  const int mrow = lane & 15;
  const int quad = lane >> 4;
  int aoff[4], boff[4];
#pragma unroll
  for (int mt = 0; mt < 4; ++mt) aoff[mt] = (wr * 64 + mt * 16 + mrow) * 32 + quad * 8;
#pragma unroll
  for (int nt = 0; nt < 4; ++nt) boff[nt] = (wc * 64 + nt * 16 + mrow) * 32 + quad * 8;

  f32x4 acc[4][4];
  const f32x4 zero = {0.f, 0.f, 0.f, 0.f};
#pragma unroll
  for (int mt = 0; mt < 4; ++mt)
#pragma unroll
    for (int nt = 0; nt < 4; ++nt) acc[mt][nt] = zero;

  for (int k0 = 0; k0 < KDIM; k0 += 64) {
    __syncthreads();
    // h=0 sub-tile (cols k0..k0+31)
    g2l16(gA + k0, lA);
    g2l16(gA + k0 + (size_t)16 * KDIM, lA + 512);
    g2l16(gB + k0, lB);
    g2l16(gB + k0 + (size_t)16 * KDIM, lB + 512);
    // h=1 sub-tile (cols k0+32..k0+63)
    g2l16(gA + k0 + 32, lA + 4096);
    g2l16(gA + k0 + 32 + (size_t)16 * KDIM, lA + 4096 + 512);
    g2l16(gB + k0 + 32, lB + 4096);
    g2l16(gB + k0 + 32 + (size_t)16 * KDIM, lB + 4096 + 512);
    __syncthreads();

    bf16x8 af[2][4], bfr[2][4];
#pragma unroll
    for (int h = 0; h < 2; ++h) {
#pragma unroll
      for (int mt = 0; mt < 4; ++mt) af[h][mt] = *(const bf16x8*)(As + h * 4096 + aoff[mt]);
#pragma unroll
      for (int nt = 0; nt < 4; ++nt) bfr[h][nt] = *(const bf16x8*)(Bs + h * 4096 + boff[nt]);
    }
#pragma unroll
    for (int h = 0; h < 2; ++h)
#pragma unroll
      for (int mt = 0; mt < 4; ++mt)
#pragma unroll
        for (int nt = 0; nt < 4; ++nt)
          acc[mt][nt] = __builtin_amdgcn_mfma_f32_16x16x32_bf16(af[h][mt], bfr[h][nt],
                                                                acc[mt][nt], 0, 0, 0);
  }

  // epilogue: C/D layout col = lane&15, row = quad*4 + reg
#pragma unroll
  for (int mt = 0; mt < 4; ++mt) {
#pragma unroll
    for (int nt = 0; nt < 4; ++nt) {
      const int col = n0 + wc * 64 + nt * 16 + mrow;
      const int rbase = m0 + wr * 64 + mt * 16 + quad * 4;
#pragma unroll
      for (int r = 0; r < 4; ++r)
        out[(size_t)(rbase + r) * OUT_F + col] = acc[mt][nt][r];
    }
  }
}

// ---------------------------------------------------------------------------
extern "C" void kernel_launch(void* const* d_in, const int* in_sizes, int n_in,
                              void* d_out, int out_size, void* d_ws, size_t ws_size,
                              hipStream_t stream) {
  const float* x  = (const float*)d_in[0];
  // d_in[1] = grid: uniform linspace, folded into closed-form basis (unused)
  const float* bw = (const float*)d_in[2];  // [OUT_F, IN_F]
  const float* sw = (const float*)d_in[3];  // [IN_F, 8, OUT_F]
  const float* sc = (const float*)d_in[4];  // [IN_F, OUT_F]
  float* out = (float*)d_out;

  __bf16* Wt = (__bf16*)d_ws;                                    // [OUT_F][KDIM] 18.9 MB
  __bf16* Ab = (__bf16*)((char*)d_ws +
                         (size_t)OUT_F * KDIM * sizeof(__bf16)); // [BATCH][KDIM] 151 MB

  build_w<<<1024, 256, 0, stream>>>(bw, sw, sc, Wt);
  build_a<<<BATCH, 256, 0, stream>>>(x, Ab);
  gemm_bt<<<(BATCH / 128) * (OUT_F / 128), 256, 0, stream>>>(Ab, Wt, out);
}